// Round 16
// baseline (185.656 us; speedup 1.0000x reference)
//
#include <hip/hip_runtime.h>
#include <cstdint>

typedef short bf8 __attribute__((ext_vector_type(8)));
typedef float f4 __attribute__((ext_vector_type(4)));

#define SEQ 2048
#define DIM 512
#define NMAT (512*512)
#define SCQ 0.04419417382415922f
#define LOG2E 1.4426950408889634f

__device__ inline unsigned short f2bf(float f){
    unsigned int u = __builtin_bit_cast(unsigned int, f);
    u = (u + 0x7FFFu + ((u >> 16) & 1u)) >> 16;
    return (unsigned short)u;
}

__device__ __forceinline__ float exp2fast(float x){
    return __builtin_amdgcn_exp2f(x);   // v_exp_f32 (base-2 native)
}

__device__ __forceinline__ void glds16(const unsigned short* gsrc, const unsigned short* ldst){
    __builtin_amdgcn_global_load_lds(
        (const __attribute__((address_space(1))) unsigned int*)gsrc,
        (__attribute__((address_space(3))) unsigned int*)ldst, 16, 0, 0);
}

// DPP butterfly reduce steps (VALU, ~4 cyc) replacing ds_bpermute shfl (~120 cyc).
// 0xB1=quad_perm xor1, 0x4E=quad_perm xor2, 0x141=row_half_mirror, 0x140=row_mirror.
template<int CTRL>
__device__ __forceinline__ float dppadd(float x){
    const int t = __builtin_amdgcn_update_dpp(0, __builtin_bit_cast(int, x), CTRL, 0xF, 0xF, true);
    return x + __builtin_bit_cast(float, t);
}
template<int CTRL>
__device__ __forceinline__ float dppmax(float x){
    const int t = __builtin_amdgcn_update_dpp(0, __builtin_bit_cast(int, x), CTRL, 0xF, 0xF, true);
    return fmaxf(x, __builtin_bit_cast(float, t));
}

// ---------------- kernel 0: W (f32 [k][n]) -> Wt (bf16 [n][k]), coalesced ----------------
__global__ void prep_w(const float* __restrict__ Wv, const float* __restrict__ Wk,
                       const float* __restrict__ Wq, unsigned short* __restrict__ Wt)
{
    __shared__ float t_lds[64][65];
    const int m = blockIdx.y;
    const float* W = (m == 0) ? Wv : ((m == 1) ? Wk : Wq);
    const int bn = (blockIdx.x & 7) * 64;
    const int bk = (blockIdx.x >> 3) * 64;
    const int tr = threadIdx.x >> 6;
    const int tc = threadIdx.x & 63;
    #pragma unroll
    for (int i = 0; i < 16; ++i){
        const int k = tr + 4 * i;
        t_lds[k][tc] = W[(size_t)(bk + k) * 512 + bn + tc];
    }
    __syncthreads();
    #pragma unroll
    for (int i = 0; i < 16; ++i){
        const int n = tr + 4 * i;
        Wt[(size_t)m * NMAT + (size_t)(bn + n) * 512 + bk + tc] = f2bf(t_lds[tc][n]);
    }
}

// ---------------- kernel 1: fused 3x GEMM (+LN / +transpose epilogue) ----------------
__global__ __launch_bounds__(512, 4) void gemm3(
    const float* __restrict__ vals, const float* __restrict__ keys, const float* __restrict__ ques,
    const unsigned short* __restrict__ Wt,
    const float* __restrict__ kg, const float* __restrict__ kbe,
    const float* __restrict__ qg, const float* __restrict__ qbe,
    unsigned short* __restrict__ vt, unsigned short* __restrict__ kbuf, unsigned short* __restrict__ qbuf)
{
    __shared__ unsigned short a_lds[64 * DIM];   // 64 KB, XOR-swizzled rows
    float* red1    = (float*)a_lds;
    float* red2    = red1 + 512;
    float* stat_mu = red2 + 512;
    float* stat_rs = stat_mu + 64;

    const int tid = threadIdx.x;
    const int wv  = tid >> 6;
    const int l   = tid & 63;
    const int g   = l >> 4;
    const int lr  = l & 15;
    const int gid = blockIdx.x;
    const int m   = gid >> 8;            // 0=v, 1=k, 2=q
    const int r0  = (gid & 255) * 64;
    const float* X = (m == 0) ? vals : ((m == 1) ? keys : ques);
    const unsigned short* W = Wt + m * NMAT;

    {
        const int row = tid >> 3;
        const int cb  = (tid & 7) * 4;
        const float* xr = X + (size_t)(r0 + row) * DIM;
        #pragma unroll
        for (int i = 0; i < 16; ++i){
            const int col = cb + i * 32;
            const float4 v = *reinterpret_cast<const float4*>(xr + col);
            ushort4 h;
            h.x = f2bf(v.x); h.y = f2bf(v.y); h.z = f2bf(v.z); h.w = f2bf(v.w);
            const int byte = ((row * DIM + col) * 2) ^ ((row & 7) << 4);
            *reinterpret_cast<ushort4*>(reinterpret_cast<char*>(a_lds) + byte) = h;
        }
    }
    __syncthreads();

    f4 acc[4][4];
    #pragma unroll
    for (int i = 0; i < 4; ++i)
        #pragma unroll
        for (int j = 0; j < 4; ++j)
            acc[i][j] = (f4){0.f, 0.f, 0.f, 0.f};

    const int nb = wv * 64;
    #pragma unroll 4
    for (int ks = 0; ks < 16; ++ks){
        const int kof = ks * 32 + g * 8;
        bf8 af[4], bfr[4];
        #pragma unroll
        for (int rt = 0; rt < 4; ++rt){
            const int row = 16 * rt + lr;
            const int byte = ((row * DIM + kof) * 2) ^ ((row & 7) << 4);
            af[rt] = *reinterpret_cast<const bf8*>(reinterpret_cast<const char*>(a_lds) + byte);
        }
        #pragma unroll
        for (int ct = 0; ct < 4; ++ct)
            bfr[ct] = *reinterpret_cast<const bf8*>(W + (size_t)(nb + 16 * ct + lr) * DIM + kof);
        #pragma unroll
        for (int rt = 0; rt < 4; ++rt)
            #pragma unroll
            for (int ct = 0; ct < 4; ++ct)
                acc[rt][ct] = __builtin_amdgcn_mfma_f32_16x16x32_bf16(af[rt], bfr[ct], acc[rt][ct], 0, 0, 0);
    }

    if (m == 0){
        __syncthreads();
        #pragma unroll
        for (int rt = 0; rt < 4; ++rt)
            #pragma unroll
            for (int r = 0; r < 4; ++r){
                const int row = 16 * rt + g * 4 + r;
                #pragma unroll
                for (int ct = 0; ct < 4; ++ct){
                    const int d = nb + 16 * ct + lr;
                    const int byte = (d * 128 + row * 2) ^ ((d & 7) << 4);
                    *reinterpret_cast<unsigned short*>(reinterpret_cast<char*>(a_lds) + byte) = f2bf(acc[rt][ct][r]);
                }
            }
        __syncthreads();
        const int bb = r0 >> 11;
        const int s0 = r0 & 2047;
        #pragma unroll
        for (int pq = 0; pq < 4; ++pq){
            const int d  = pq * 128 + (tid >> 2);
            const int sc = (tid & 3) * 16;
            const int base = d * 128 + sc * 2;
            const int sw = (d & 7) << 4;
            const bf8 x0 = *reinterpret_cast<const bf8*>(reinterpret_cast<const char*>(a_lds) + (base ^ sw));
            const bf8 x1 = *reinterpret_cast<const bf8*>(reinterpret_cast<const char*>(a_lds) + ((base + 16) ^ sw));
            unsigned short* dst = vt + (size_t)(bb * 512 + d) * SEQ + s0 + sc;
            *reinterpret_cast<bf8*>(dst)     = x0;
            *reinterpret_cast<bf8*>(dst + 8) = x1;
        }
        return;
    }

    const float* gamma = (m == 1) ? kg  : qg;
    const float* beta  = (m == 1) ? kbe : qbe;
    const float scale  = (m == 1) ? 1.0f : SCQ * LOG2E;
    unsigned short* outp = (m == 1) ? kbuf : qbuf;

    __syncthreads();
    #pragma unroll
    for (int rt = 0; rt < 4; ++rt){
        #pragma unroll
        for (int r = 0; r < 4; ++r){
            float s1 = 0.f, s2 = 0.f;
            #pragma unroll
            for (int ct = 0; ct < 4; ++ct){ const float v = acc[rt][ct][r]; s1 += v; s2 += v * v; }
            s1 = dppadd<0xB1>(s1); s1 = dppadd<0x4E>(s1); s1 = dppadd<0x141>(s1); s1 = dppadd<0x140>(s1);
            s2 = dppadd<0xB1>(s2); s2 = dppadd<0x4E>(s2); s2 = dppadd<0x141>(s2); s2 = dppadd<0x140>(s2);
            if (lr == 0){
                const int row = 16 * rt + g * 4 + r;
                red1[row * 8 + wv] = s1;
                red2[row * 8 + wv] = s2;
            }
        }
    }
    __syncthreads();
    if (tid < 64){
        float S1 = 0.f, S2 = 0.f;
        #pragma unroll
        for (int w = 0; w < 8; ++w){ S1 += red1[tid * 8 + w]; S2 += red2[tid * 8 + w]; }
        const float mu = S1 * (1.0f / 512.0f);
        const float var = S2 * (1.0f / 512.0f) - mu * mu;
        stat_mu[tid] = mu;
        stat_rs[tid] = rsqrtf(var + 1e-5f);
    }
    __syncthreads();
    #pragma unroll
    for (int rt = 0; rt < 4; ++rt){
        #pragma unroll
        for (int r = 0; r < 4; ++r){
            const int row = 16 * rt + g * 4 + r;
            const float mu = stat_mu[row];
            const float rs = stat_rs[row];
            #pragma unroll
            for (int ct = 0; ct < 4; ++ct){
                const int d = nb + 16 * ct + lr;
                const float v = ((acc[rt][ct][r] - mu) * rs * gamma[d] + beta[d]) * scale;
                outp[(size_t)(r0 + row) * DIM + d] = f2bf(v);
            }
        }
    }
}

// ---------------- kernel 2: flash attention, KB=32, depth-3 single-barrier pipeline ----------------
// grid 256 = 8 batch * 32 p. Rows 0-31 = qt=p (light), rows 32-63 = qt=63-p.
// Per iteration j (ONE barrier): stage K(j+2) [ring-3 slot (j+2)%3] ||
//   vmcnt(4) [drains V(j-2)+A(j-1), all >=1 iter old; keeps A(j) in flight] ||
//   PV(j-2) [P/fac dbuf (j-2)&1, vst=V(j-2)] || load V(j-1) into vst (after PV!) ||
//   QK(j) -> S dbuf[j&1] || softmax(j-1) [S dbuf (j-1)&1 -> P/fac (j-1)&1] ||
//   lgkmcnt(0); barrier.
// QK MFMA, PV MFMA, softmax VALU share one phase -> pipe-level overlap.
// Cross-wave glds safety: A(j) retires at iter j+1's vmcnt(4), before the barrier
// preceding QK(j+2)'s reads. Ring-3 WAR: tile in slot (j+2)%3 was read by QK(j-1),
// ds-drained at end-of-(j-1) barrier. P rows 80B (16B-aligned, 2-way-bank-free).
__global__ __launch_bounds__(512, 2) void attn(
    const unsigned short* __restrict__ qb, const unsigned short* __restrict__ kb,
    const unsigned short* __restrict__ vt, const float* __restrict__ qin,
    const float* __restrict__ g_o, const float* __restrict__ b_o,
    float* __restrict__ outp)
{
    __shared__ unsigned short k_lds[3 * 32 * DIM];   // 96 KB ring-3, swizzled content
    __shared__ float s_dbuf[2][64][36];              // 18.4 KB S double-buffer
    __shared__ unsigned short p_dbuf[2][64 * 40];    // 20 KB P dbuf: 80B rows
    __shared__ float fac_dbuf[2][64];
    __shared__ float l_lds[64];
    // epilogue reduction arrays alias s_dbuf (dead after last softmax)
    float* red1    = &s_dbuf[0][0][0];
    float* red2    = red1 + 512;
    float* stat_mu = red2 + 512;
    float* stat_rs = stat_mu + 64;

    const int tid = threadIdx.x;
    const int wv  = tid >> 6;
    const int l   = tid & 63;
    const int g   = l >> 4;
    const int lr  = l & 15;
    const int b   = blockIdx.x & 7;
    const int p   = blockIdx.x >> 3;      // 0..31
    const int q0a = 32 * p;               // rows 0..31  (light)
    const int q0b = 32 * (63 - p);        // rows 32..63 (heavy)
    const int n   = 64 - p;               // 32-kv tiles (33..64)

    const int ct  = wv & 1;               // QK col tile (16 cols of 32)
    const int rt_ = wv >> 1;              // QK row tile (16 rows), 0..3

    // Q fragments: rows 16*rt_+lr, full K=512 (qf[16] = 64 VGPR)
    bf8 qf[16];
    {
        const int row = 16 * rt_ + lr;
        const int qglob = (row < 32) ? (q0a + row) : (q0b + row - 32);
        const unsigned short* qr = qb + (size_t)(b * SEQ + qglob) * DIM + g * 8;
        #pragma unroll
        for (int ks = 0; ks < 16; ++ks)
            qf[ks] = *reinterpret_cast<const bf8*>(qr + ks * 32);
    }

    // K staging: glds into explicit ring slot (rows 4wv..4wv+3), linear dest +
    // inverse-swizzled source. Tail dummies keep DEST = the free slot, source tile 0.
    auto kglds = [&](int slot, int t){
        const int bo = slot * (32 * DIM);
        #pragma unroll
        for (int i = 0; i < 4; ++i){
            const int row = 4 * wv + i;
            glds16(kb + (size_t)(b * SEQ + t * 32 + row) * DIM + ((l * 8) ^ ((row & 7) * 8)),
                   k_lds + bo + row * DIM);
        }
    };

    kglds(0, 0);
    kglds(1, 1);

    // running softmax stats in REGISTERS (row = tid>>3 thread-stable; 8 copies/row)
    float m_reg = -__builtin_inff();
    float l_reg = 0.0f;

    f4 acc[4][4];
    #pragma unroll
    for (int rt = 0; rt < 4; ++rt)
        #pragma unroll
        for (int cv = 0; cv < 4; ++cv)
            acc[rt][cv] = (f4){0.f, 0.f, 0.f, 0.f};
    bf8 vst[4];   // V fragments for one 32-kv tile (single buffer; PV-before-load)

    // prologue drain: K(0), K(1), Q frags
    asm volatile("s_waitcnt vmcnt(0)" ::: "memory");
    __builtin_amdgcn_s_barrier();
    __builtin_amdgcn_sched_barrier(0);

    // PV for tile jp: consumes p_dbuf/fac_dbuf[jp&1] + vst (= V(jp))
    auto do_pv = [&](int jp){
        const bool frozen = (jp > p);
        const char* pb  = reinterpret_cast<const char*>(p_dbuf[jp & 1]);
        const float* fc = fac_dbuf[jp & 1];
        __builtin_amdgcn_s_setprio(1);
        #pragma unroll
        for (int rt = 0; rt < 4; ++rt){
            if (rt < 2 && frozen) continue;    // light rows frozen
            float f[4];
            #pragma unroll
            for (int r = 0; r < 4; ++r) f[r] = fc[16 * rt + 4 * g + r];
            #pragma unroll
            for (int cv = 0; cv < 4; ++cv)
                #pragma unroll
                for (int r = 0; r < 4; ++r)
                    acc[rt][cv][r] *= f[r];
            const bf8 pa = *reinterpret_cast<const bf8*>(pb + (16 * rt + lr) * 80 + g * 16);
            #pragma unroll
            for (int cv = 0; cv < 4; ++cv)
                acc[rt][cv] = __builtin_amdgcn_mfma_f32_16x16x32_bf16(pa, vst[cv], acc[rt][cv], 0, 0, 0);
        }
        __builtin_amdgcn_s_setprio(0);
    };

    // softmax for tile tj: reads s_dbuf[tj&1], writes p_dbuf/fac_dbuf[tj&1]
    auto do_sm = [&](int tj){
        const int row = tid >> 3;
        const int cp  = tid & 7;
        if (row >= 32 || tj <= p){
            const float4 x0 = *reinterpret_cast<const float4*>(&s_dbuf[tj & 1][row][4 * cp]);
            float av[4] = {x0.x, x0.y, x0.z, x0.w};
            const int qrow = (row < 32) ? (q0a + row) : (q0b + row - 32);
            const int kc = 32 * tj + 4 * cp;
            #pragma unroll
            for (int jj = 0; jj < 4; ++jj)
                if (kc + jj > qrow) av[jj] = -1e30f;
            float pm = fmaxf(fmaxf(av[0], av[1]), fmaxf(av[2], av[3]));
            pm = dppmax<0xB1>(pm); pm = dppmax<0x4E>(pm); pm = dppmax<0x141>(pm);
            const float mo = m_reg;
            const float mn = fmaxf(mo, pm);
            float e[4];
            #pragma unroll
            for (int jj = 0; jj < 4; ++jj) e[jj] = exp2fast(av[jj] - mn);
            float ts = (e[0] + e[1]) + (e[2] + e[3]);
            ts = dppadd<0xB1>(ts); ts = dppadd<0x4E>(ts); ts = dppadd<0x141>(ts);
            const float fc = exp2fast(mo - mn);
            m_reg = mn;
            l_reg = l_reg * fc + ts;
            if (cp == 0) fac_dbuf[tj & 1][row] = fc;
            uint2 pk;
            pk.x = (unsigned int)f2bf(e[0]) | ((unsigned int)f2bf(e[1]) << 16);
            pk.y = (unsigned int)f2bf(e[2]) | ((unsigned int)f2bf(e[3]) << 16);
            *reinterpret_cast<uint2*>(reinterpret_cast<char*>(p_dbuf[tj & 1]) +
                row * 80 + cp * 8) = pk;
        }
    };

    for (int j = 0; j < n; ++j){
        // stage K(j+2) into slot (j+2)%3 (holds tile j-1, ds-drained at end of j-1)
        kglds((j + 2) % 3, j + 2 < n ? j + 2 : 0);

        // drain V(j-2) and A(j-1): all >= ~1 iteration old (keeps this iter's glds)
        asm volatile("s_waitcnt vmcnt(4)" ::: "memory");
        __builtin_amdgcn_sched_barrier(0);   // rule 18: PV MFMAs read vst regs

        if (j >= 2) do_pv(j - 2);

        // V(j-1) loads AFTER PV consumed vst=V(j-2) (no clobber)
        if (j >= 1){
            const int k0 = 32 * (j - 1);
            #pragma unroll
            for (int cv = 0; cv < 4; ++cv)
                vst[cv] = *reinterpret_cast<const bf8*>(
                    vt + (size_t)(b * DIM + 64 * wv + 16 * cv + lr) * SEQ + k0 + g * 8);
        }

        // QK(j): wave (rt_, ct), 16x16 S tile over K=512
        if (rt_ >= 2 || j <= p){
            const int krow  = 16 * ct + lr;
            const int rbase = krow * 1024;
            const int rx    = (krow & 7) << 4;
            const char* kbuf = reinterpret_cast<const char*>(k_lds) + (j % 3) * 32768;
            __builtin_amdgcn_s_setprio(1);
            f4 sa[4];
            sa[0] = (f4){0.f,0.f,0.f,0.f}; sa[1] = (f4){0.f,0.f,0.f,0.f};
            sa[2] = (f4){0.f,0.f,0.f,0.f}; sa[3] = (f4){0.f,0.f,0.f,0.f};
            #pragma unroll
            for (int ks = 0; ks < 16; ++ks){
                const bf8 bk = *reinterpret_cast<const bf8*>(
                    kbuf + rbase + ((ks * 64 + g * 16) ^ rx));
                sa[ks & 3] = __builtin_amdgcn_mfma_f32_16x16x32_bf16(qf[ks], bk, sa[ks & 3], 0, 0, 0);
            }
            const f4 s = (sa[0] + sa[1]) + (sa[2] + sa[3]);
            const int srow = 16 * rt_ + 4 * g;
            #pragma unroll
            for (int r = 0; r < 4; ++r)
                s_dbuf[j & 1][srow + r][16 * ct + lr] = s[r];
            __builtin_amdgcn_s_setprio(0);
        }

        // softmax(j-1): independent of QK(j) (reads other S buffer) -> same phase
        if (j >= 1) do_sm(j - 1);

        asm volatile("s_waitcnt lgkmcnt(0)" ::: "memory");
        __builtin_amdgcn_s_barrier();
        __builtin_amdgcn_sched_barrier(0);
    }

    // ---- tail: PV(n-2), softmax(n-1), PV(n-1) ----
    asm volatile("s_waitcnt vmcnt(0)" ::: "memory");   // V(n-2) (loaded iter n-1)
    __builtin_amdgcn_sched_barrier(0);
    do_pv(n - 2);
    {
        const int k0 = 32 * (n - 1);
        #pragma unroll
        for (int cv = 0; cv < 4; ++cv)
            vst[cv] = *reinterpret_cast<const bf8*>(
                vt + (size_t)(b * DIM + 64 * wv + 16 * cv + lr) * SEQ + k0 + g * 8);
    }
    do_sm(n - 1);
    asm volatile("s_waitcnt lgkmcnt(0)" ::: "memory");
    __builtin_amdgcn_s_barrier();
    __builtin_amdgcn_sched_barrier(0);
    asm volatile("s_waitcnt vmcnt(0)" ::: "memory");   // V(n-1)
    __builtin_amdgcn_sched_barrier(0);
    do_pv(n - 1);

    // publish register l to LDS for the epilogue's (different) thread mapping
    if ((tid & 7) == 0) l_lds[tid >> 3] = l_reg;
    __syncthreads();   // l_lds visible; also all softmax LDS traffic done

    // ---- finalize: /l, +residual, LN, store (64 rows) ----
    float li[4][4];
    #pragma unroll
    for (int rt = 0; rt < 4; ++rt)
        #pragma unroll
        for (int r = 0; r < 4; ++r)
            li[rt][r] = 1.0f / l_lds[16 * rt + 4 * g + r];
    #pragma unroll
    for (int rt = 0; rt < 4; ++rt){
        #pragma unroll
        for (int cv = 0; cv < 4; ++cv){
            #pragma unroll
            for (int r = 0; r < 4; ++r){
                const int row = 16 * rt + 4 * g + r;
                const int qglob = (row < 32) ? (q0a + row) : (q0b + row - 32);
                const int d = 64 * wv + 16 * cv + lr;
                acc[rt][cv][r] = acc[rt][cv][r] * li[rt][r]
                               + qin[(size_t)(b * SEQ + qglob) * DIM + d];
            }
        }
    }
    __syncthreads();   // s_dbuf fully dead (aliased by red1/red2 below)
    #pragma unroll
    for (int rt = 0; rt < 4; ++rt){
        #pragma unroll
        for (int r = 0; r < 4; ++r){
            float s1 = 0.f, s2 = 0.f;
            #pragma unroll
            for (int cv = 0; cv < 4; ++cv){ const float v = acc[rt][cv][r]; s1 += v; s2 += v * v; }
            s1 = dppadd<0xB1>(s1); s1 = dppadd<0x4E>(s1); s1 = dppadd<0x141>(s1); s1 = dppadd<0x140>(s1);
            s2 = dppadd<0xB1>(s2); s2 = dppadd<0x4E>(s2); s2 = dppadd<0x141>(s2); s2 = dppadd<0x140>(s2);
            if (lr == 0){
                const int row = 16 * rt + 4 * g + r;
                red1[row * 8 + wv] = s1;
                red2[row * 8 + wv] = s2;
            }
        }
    }
    __syncthreads();
    if (tid < 64){
        float S1 = 0.f, S2 = 0.f;
        #pragma unroll
        for (int w = 0; w < 8; ++w){ S1 += red1[tid * 8 + w]; S2 += red2[tid * 8 + w]; }
        const float mu = S1 * (1.0f / 512.0f);
        const float var = S2 * (1.0f / 512.0f) - mu * mu;
        stat_mu[tid] = mu;
        stat_rs[tid] = rsqrtf(var + 1e-5f);
    }
    __syncthreads();
    #pragma unroll
    for (int rt = 0; rt < 4; ++rt){
        #pragma unroll
        for (int r = 0; r < 4; ++r){
            const int row = 16 * rt + 4 * g + r;
            const int qglob = (row < 32) ? (q0a + row) : (q0b + row - 32);
            const float mu = stat_mu[row];
            const float rs = stat_rs[row];
            #pragma unroll
            for (int cv = 0; cv < 4; ++cv){
                const int d = 64 * wv + 16 * cv + lr;
                outp[(size_t)(b * SEQ + qglob) * DIM + d] =
                    (acc[rt][cv][r] - mu) * rs * g_o[d] + b_o[d];
            }
        }
    }
}

extern "C" void kernel_launch(void* const* d_in, const int* in_sizes, int n_in,
                              void* d_out, int out_size, void* d_ws, size_t ws_size,
                              hipStream_t stream)
{
    (void)in_sizes; (void)n_in; (void)out_size; (void)ws_size;
    const float* vals = (const float*)d_in[0];
    const float* keys = (const float*)d_in[1];
    const float* ques = (const float*)d_in[2];
    const float* Wv   = (const float*)d_in[5];
    const float* Wk   = (const float*)d_in[6];
    const float* Wq   = (const float*)d_in[7];
    const float* ln_k_g = (const float*)d_in[8];
    const float* ln_k_b = (const float*)d_in[9];
    const float* ln_q_g = (const float*)d_in[10];
    const float* ln_q_b = (const float*)d_in[11];
    const float* ln_o_g = (const float*)d_in[12];
    const float* ln_o_b = (const float*)d_in[13];
    float* outp = (float*)d_out;

    char* ws = (char*)d_ws;
    unsigned short* qbuf = (unsigned short*)(ws);
    unsigned short* kbuf = (unsigned short*)(ws + (size_t)16 * 1024 * 1024);
    unsigned short* vt   = (unsigned short*)(ws + (size_t)32 * 1024 * 1024);
    unsigned short* Wt   = (unsigned short*)(ws + (size_t)48 * 1024 * 1024);

    prep_w<<<dim3(64, 3), 256, 0, stream>>>(Wv, Wk, Wq, Wt);

    gemm3<<<768, 512, 0, stream>>>(vals, keys, ques, Wt,
                                   ln_k_g, ln_k_b, ln_q_g, ln_q_b,
                                   vt, kbuf, qbuf);

    attn<<<256, 512, 0, stream>>>(qbuf, kbuf, vt, ques, ln_o_g, ln_o_b, outp);
}

// Round 17
// 184.777 us; speedup vs baseline: 1.0048x; 1.0048x over previous
//
#include <hip/hip_runtime.h>
#include <cstdint>

typedef short bf8 __attribute__((ext_vector_type(8)));
typedef float f4 __attribute__((ext_vector_type(4)));

#define SEQ 2048
#define DIM 512
#define NMAT (512*512)
#define SCQ 0.04419417382415922f
#define LOG2E 1.4426950408889634f

__device__ inline unsigned short f2bf(float f){
    unsigned int u = __builtin_bit_cast(unsigned int, f);
    u = (u + 0x7FFFu + ((u >> 16) & 1u)) >> 16;
    return (unsigned short)u;
}

__device__ __forceinline__ float exp2fast(float x){
    return __builtin_amdgcn_exp2f(x);   // v_exp_f32 (base-2 native)
}

__device__ __forceinline__ void glds16(const unsigned short* gsrc, const unsigned short* ldst){
    __builtin_amdgcn_global_load_lds(
        (const __attribute__((address_space(1))) unsigned int*)gsrc,
        (__attribute__((address_space(3))) unsigned int*)ldst, 16, 0, 0);
}

// DPP butterfly reduce steps (VALU, ~4 cyc) replacing ds_bpermute shfl (~120 cyc).
// 0xB1=quad_perm xor1, 0x4E=quad_perm xor2, 0x141=row_half_mirror, 0x140=row_mirror.
template<int CTRL>
__device__ __forceinline__ float dppadd(float x){
    const int t = __builtin_amdgcn_update_dpp(0, __builtin_bit_cast(int, x), CTRL, 0xF, 0xF, true);
    return x + __builtin_bit_cast(float, t);
}
template<int CTRL>
__device__ __forceinline__ float dppmax(float x){
    const int t = __builtin_amdgcn_update_dpp(0, __builtin_bit_cast(int, x), CTRL, 0xF, 0xF, true);
    return fmaxf(x, __builtin_bit_cast(float, t));
}

// ---------------- kernel 0: W (f32 [k][n]) -> Wt (bf16 [n][k]), coalesced ----------------
// 64x64 tile per block via LDS transpose: coalesced f32 reads, coalesced bf16 writes.
__global__ void prep_w(const float* __restrict__ Wv, const float* __restrict__ Wk,
                       const float* __restrict__ Wq, unsigned short* __restrict__ Wt)
{
    __shared__ float t_lds[64][65];
    const int m = blockIdx.y;
    const float* W = (m == 0) ? Wv : ((m == 1) ? Wk : Wq);
    const int bn = (blockIdx.x & 7) * 64;
    const int bk = (blockIdx.x >> 3) * 64;
    const int tr = threadIdx.x >> 6;
    const int tc = threadIdx.x & 63;
    #pragma unroll
    for (int i = 0; i < 16; ++i){
        const int k = tr + 4 * i;
        t_lds[k][tc] = W[(size_t)(bk + k) * 512 + bn + tc];
    }
    __syncthreads();
    #pragma unroll
    for (int i = 0; i < 16; ++i){
        const int n = tr + 4 * i;
        Wt[(size_t)m * NMAT + (size_t)(bn + n) * 512 + bk + tc] = f2bf(t_lds[tc][n]);
    }
}

// ---------------- kernel 1: fused 3x GEMM (+LN / +transpose epilogue) ----------------
// __launch_bounds__(512, 4): 4 waves/EU -> 2 blocks/CU co-resident (LDS 2x64KB=128KB,
// VGPR capped at 128). Overlaps one block's staging/epilogue with another's K-loop
// and doubles the waves hiding the L2 latency of the in-loop W-fragment loads.
__global__ __launch_bounds__(512, 4) void gemm3(
    const float* __restrict__ vals, const float* __restrict__ keys, const float* __restrict__ ques,
    const unsigned short* __restrict__ Wt,
    const float* __restrict__ kg, const float* __restrict__ kbe,
    const float* __restrict__ qg, const float* __restrict__ qbe,
    unsigned short* __restrict__ vt, unsigned short* __restrict__ kbuf, unsigned short* __restrict__ qbuf)
{
    __shared__ unsigned short a_lds[64 * DIM];   // 64 KB, XOR-swizzled rows
    float* red1    = (float*)a_lds;
    float* red2    = red1 + 512;
    float* stat_mu = red2 + 512;
    float* stat_rs = stat_mu + 64;

    const int tid = threadIdx.x;
    const int wv  = tid >> 6;
    const int l   = tid & 63;
    const int g   = l >> 4;
    const int lr  = l & 15;
    const int gid = blockIdx.x;
    const int m   = gid >> 8;            // 0=v, 1=k, 2=q
    const int r0  = (gid & 255) * 64;
    const float* X = (m == 0) ? vals : ((m == 1) ? keys : ques);
    const unsigned short* W = Wt + m * NMAT;

    {
        const int row = tid >> 3;
        const int cb  = (tid & 7) * 4;
        const float* xr = X + (size_t)(r0 + row) * DIM;
        #pragma unroll
        for (int i = 0; i < 16; ++i){
            const int col = cb + i * 32;
            const float4 v = *reinterpret_cast<const float4*>(xr + col);
            ushort4 h;
            h.x = f2bf(v.x); h.y = f2bf(v.y); h.z = f2bf(v.z); h.w = f2bf(v.w);
            const int byte = ((row * DIM + col) * 2) ^ ((row & 7) << 4);
            *reinterpret_cast<ushort4*>(reinterpret_cast<char*>(a_lds) + byte) = h;
        }
    }
    __syncthreads();

    f4 acc[4][4];
    #pragma unroll
    for (int i = 0; i < 4; ++i)
        #pragma unroll
        for (int j = 0; j < 4; ++j)
            acc[i][j] = (f4){0.f, 0.f, 0.f, 0.f};

    const int nb = wv * 64;
    #pragma unroll 4
    for (int ks = 0; ks < 16; ++ks){
        const int kof = ks * 32 + g * 8;
        bf8 af[4], bfr[4];
        #pragma unroll
        for (int rt = 0; rt < 4; ++rt){
            const int row = 16 * rt + lr;
            const int byte = ((row * DIM + kof) * 2) ^ ((row & 7) << 4);
            af[rt] = *reinterpret_cast<const bf8*>(reinterpret_cast<const char*>(a_lds) + byte);
        }
        #pragma unroll
        for (int ct = 0; ct < 4; ++ct)
            bfr[ct] = *reinterpret_cast<const bf8*>(W + (size_t)(nb + 16 * ct + lr) * DIM + kof);
        #pragma unroll
        for (int rt = 0; rt < 4; ++rt)
            #pragma unroll
            for (int ct = 0; ct < 4; ++ct)
                acc[rt][ct] = __builtin_amdgcn_mfma_f32_16x16x32_bf16(af[rt], bfr[ct], acc[rt][ct], 0, 0, 0);
    }

    if (m == 0){
        __syncthreads();
        #pragma unroll
        for (int rt = 0; rt < 4; ++rt)
            #pragma unroll
            for (int r = 0; r < 4; ++r){
                const int row = 16 * rt + g * 4 + r;
                #pragma unroll
                for (int ct = 0; ct < 4; ++ct){
                    const int d = nb + 16 * ct + lr;
                    const int byte = (d * 128 + row * 2) ^ ((d & 7) << 4);
                    *reinterpret_cast<unsigned short*>(reinterpret_cast<char*>(a_lds) + byte) = f2bf(acc[rt][ct][r]);
                }
            }
        __syncthreads();
        const int bb = r0 >> 11;
        const int s0 = r0 & 2047;
        #pragma unroll
        for (int pq = 0; pq < 4; ++pq){
            const int d  = pq * 128 + (tid >> 2);
            const int sc = (tid & 3) * 16;
            const int base = d * 128 + sc * 2;
            const int sw = (d & 7) << 4;
            const bf8 x0 = *reinterpret_cast<const bf8*>(reinterpret_cast<const char*>(a_lds) + (base ^ sw));
            const bf8 x1 = *reinterpret_cast<const bf8*>(reinterpret_cast<const char*>(a_lds) + ((base + 16) ^ sw));
            unsigned short* dst = vt + (size_t)(bb * 512 + d) * SEQ + s0 + sc;
            *reinterpret_cast<bf8*>(dst)     = x0;
            *reinterpret_cast<bf8*>(dst + 8) = x1;
        }
        return;
    }

    const float* gamma = (m == 1) ? kg  : qg;
    const float* beta  = (m == 1) ? kbe : qbe;
    // q gets SCQ * log2(e): softmax runs in exp2 domain (v_exp_f32 is base-2)
    const float scale  = (m == 1) ? 1.0f : SCQ * LOG2E;
    unsigned short* outp = (m == 1) ? kbuf : qbuf;

    __syncthreads();
    #pragma unroll
    for (int rt = 0; rt < 4; ++rt){
        #pragma unroll
        for (int r = 0; r < 4; ++r){
            float s1 = 0.f, s2 = 0.f;
            #pragma unroll
            for (int ct = 0; ct < 4; ++ct){ const float v = acc[rt][ct][r]; s1 += v; s2 += v * v; }
            // 16-lane reduce via DPP (was 4x2 ds_bpermute shfl chains)
            s1 = dppadd<0xB1>(s1); s1 = dppadd<0x4E>(s1); s1 = dppadd<0x141>(s1); s1 = dppadd<0x140>(s1);
            s2 = dppadd<0xB1>(s2); s2 = dppadd<0x4E>(s2); s2 = dppadd<0x141>(s2); s2 = dppadd<0x140>(s2);
            if (lr == 0){
                const int row = 16 * rt + g * 4 + r;
                red1[row * 8 + wv] = s1;
                red2[row * 8 + wv] = s2;
            }
        }
    }
    __syncthreads();
    if (tid < 64){
        float S1 = 0.f, S2 = 0.f;
        #pragma unroll
        for (int w = 0; w < 8; ++w){ S1 += red1[tid * 8 + w]; S2 += red2[tid * 8 + w]; }
        const float mu = S1 * (1.0f / 512.0f);
        const float var = S2 * (1.0f / 512.0f) - mu * mu;
        stat_mu[tid] = mu;
        stat_rs[tid] = rsqrtf(var + 1e-5f);
    }
    __syncthreads();
    #pragma unroll
    for (int rt = 0; rt < 4; ++rt){
        #pragma unroll
        for (int r = 0; r < 4; ++r){
            const int row = 16 * rt + g * 4 + r;
            const float mu = stat_mu[row];
            const float rs = stat_rs[row];
            #pragma unroll
            for (int ct = 0; ct < 4; ++ct){
                const int d = nb + 16 * ct + lr;
                const float v = ((acc[rt][ct][r] - mu) * rs * gamma[d] + beta[d]) * scale;
                outp[(size_t)(r0 + row) * DIM + d] = f2bf(v);
            }
        }
    }
}

// ---------------- kernel 2: flash attention, KB=64 (round-9 structure) ----------------
// grid 256 = 8 batch * 32 p. Rows 0-31 = qt=p (light), rows 32-63 = qt=63-p.
// Iteration j: phase1 = {glds K(2j+2,2j+3), PV(j-1), V(j) loads, QK(j)};
// b1 = lgkm only; phase2 = softmax(j) (exp2 domain, DPP reduces, m/l in regs);
// b2 = vmcnt(8) (drains 8 K glds, 8 V loads stay in flight). K ring-4 (128 KB).
__global__ __launch_bounds__(512, 2) void attn(
    const unsigned short* __restrict__ qb, const unsigned short* __restrict__ kb,
    const unsigned short* __restrict__ vt, const float* __restrict__ qin,
    const float* __restrict__ g_o, const float* __restrict__ b_o,
    float* __restrict__ outp)
{
    __shared__ unsigned short k_lds[4 * 32 * DIM];   // 128 KB ring-4, swizzled content
    __shared__ float s_lds[64][68];                  // 17.4 KB: 64x64 S + pad
    __shared__ unsigned short p_lds[64 * 64];        // 8 KB: 128B rows, XOR swz
    __shared__ float l_lds[64], fac_lds[64];
    // epilogue reduction arrays alias s_lds (dead after last softmax)
    float* red1    = &s_lds[0][0];
    float* red2    = red1 + 512;
    float* stat_mu = red2 + 512;
    float* stat_rs = stat_mu + 64;

    const int tid = threadIdx.x;
    const int wv  = tid >> 6;
    const int l   = tid & 63;
    const int g   = l >> 4;
    const int lr  = l & 15;
    const int b   = blockIdx.x & 7;
    const int p   = blockIdx.x >> 3;      // 0..31
    const int q0a = 32 * p;               // rows 0..31  (light)
    const int q0b = 32 * (63 - p);        // rows 32..63 (heavy)
    const int n2  = (65 - p) >> 1;        // kv pairs (17..32)
    const int jL  = p >> 1;               // last pair with light rows active

    const int ct  = wv & 1;               // QK col tile (16 cols within 32-tile)
    const int rt_ = wv >> 1;              // QK row tile (16 rows), 0..3

    // Q fragments: rows 16*rt_+lr, full K=512 (qf[16] = 64 VGPR)
    bf8 qf[16];
    {
        const int row = 16 * rt_ + lr;
        const int qglob = (row < 32) ? (q0a + row) : (q0b + row - 32);
        const unsigned short* qr = qb + (size_t)(b * SEQ + qglob) * DIM + g * 8;
        #pragma unroll
        for (int ks = 0; ks < 16; ++ks)
            qf[ks] = *reinterpret_cast<const bf8*>(qr + ks * 32);
    }

    // K staging: glds, linear dest + inverse-swizzled source (rows 4wv..4wv+3)
    auto kglds = [&](int t){
        const int bo = (t & 3) * (32 * DIM);
        #pragma unroll
        for (int i = 0; i < 4; ++i){
            const int row = 4 * wv + i;
            glds16(kb + (size_t)(b * SEQ + t * 32 + row) * DIM + ((l * 8) ^ ((row & 7) * 8)),
                   k_lds + bo + row * DIM);
        }
    };

    kglds(0);
    kglds(1);

    // running softmax stats in REGISTERS (row = tid>>3 is thread-stable;
    // all 8 threads of a row keep identical copies)
    float m_reg = -__builtin_inff();
    float l_reg = 0.0f;

    f4 acc[4][4];
    #pragma unroll
    for (int rt = 0; rt < 4; ++rt)
        #pragma unroll
        for (int cv = 0; cv < 4; ++cv)
            acc[rt][cv] = (f4){0.f, 0.f, 0.f, 0.f};
    bf8 vst[8];   // [cv][ks]: V fragments for current 64-kv chunk

    // prologue drain: K(0), K(1), Q frags
    asm volatile("s_waitcnt vmcnt(0)" ::: "memory");
    __builtin_amdgcn_s_barrier();
    __builtin_amdgcn_sched_barrier(0);

    // PV helper: consumes p_lds/fac (pair jp) + vst (V of pair jp)
    auto do_pv = [&](int jp){
        const bool frozen = (jp > jL);
        __builtin_amdgcn_s_setprio(1);
        #pragma unroll
        for (int rt = 0; rt < 4; ++rt){
            if (rt < 2 && frozen) continue;    // light rows frozen
            float f[4];
            #pragma unroll
            for (int r = 0; r < 4; ++r) f[r] = fac_lds[16 * rt + 4 * g + r];
            #pragma unroll
            for (int cv = 0; cv < 4; ++cv)
                #pragma unroll
                for (int r = 0; r < 4; ++r)
                    acc[rt][cv][r] *= f[r];
            const int prow = 16 * rt + lr;
            const int sw = (prow & 7) << 4;
            const bf8 pa0 = *reinterpret_cast<const bf8*>(
                reinterpret_cast<const char*>(p_lds) + prow * 128 + ((g * 16) ^ sw));
            const bf8 pa1 = *reinterpret_cast<const bf8*>(
                reinterpret_cast<const char*>(p_lds) + prow * 128 + ((64 + g * 16) ^ sw));
            #pragma unroll
            for (int cv = 0; cv < 4; ++cv){
                acc[rt][cv] = __builtin_amdgcn_mfma_f32_16x16x32_bf16(pa0, vst[2 * cv],     acc[rt][cv], 0, 0, 0);
                acc[rt][cv] = __builtin_amdgcn_mfma_f32_16x16x32_bf16(pa1, vst[2 * cv + 1], acc[rt][cv], 0, 0, 0);
            }
        }
        __builtin_amdgcn_s_setprio(0);
    };

    for (int j = 0; j < n2; ++j){
        const int k0 = 64 * j;
        const int tp = 2 * j + 2;
        if (tp     < 2 * n2) kglds(tp);
        if (tp + 1 < 2 * n2) kglds(tp + 1);

        // ---- PV for previous pair (vst = V(j-1)) ----
        if (j > 0) do_pv(j - 1);

        // ---- V(j) loads: 64 kv cols (consumed next iter / final) ----
        #pragma unroll
        for (int cv = 0; cv < 4; ++cv)
            #pragma unroll
            for (int ks = 0; ks < 2; ++ks)
                vst[2 * cv + ks] = *reinterpret_cast<const bf8*>(
                    vt + (size_t)(b * DIM + 64 * wv + 16 * cv + lr) * SEQ + k0 + 32 * ks + g * 8);

        // ---- QK(j): wave (rt_, ct), two 32-col halves, full K=512 each ----
        if (rt_ >= 2 || j <= jL){
            const int krow  = 16 * ct + lr;
            const int rbase = krow * 1024;
            const int rx    = (krow & 7) << 4;
            __builtin_amdgcn_s_setprio(1);
            #pragma unroll
            for (int h = 0; h < 2; ++h){
                const char* kbuf = reinterpret_cast<const char*>(k_lds) + ((2 * j + h) & 3) * 32768;
                f4 sa[4];
                sa[0] = (f4){0.f,0.f,0.f,0.f}; sa[1] = (f4){0.f,0.f,0.f,0.f};
                sa[2] = (f4){0.f,0.f,0.f,0.f}; sa[3] = (f4){0.f,0.f,0.f,0.f};
                #pragma unroll
                for (int ks = 0; ks < 16; ++ks){
                    const bf8 bk = *reinterpret_cast<const bf8*>(
                        kbuf + rbase + ((ks * 64 + g * 16) ^ rx));
                    sa[ks & 3] = __builtin_amdgcn_mfma_f32_16x16x32_bf16(qf[ks], bk, sa[ks & 3], 0, 0, 0);
                }
                const f4 s = (sa[0] + sa[1]) + (sa[2] + sa[3]);
                const int srow = 16 * rt_ + 4 * g;
                #pragma unroll
                for (int r = 0; r < 4; ++r)
                    s_lds[srow + r][32 * h + 16 * ct + lr] = s[r];
            }
            __builtin_amdgcn_s_setprio(0);
        }
        // b1: S visible; NO vmem drain (K/V loads stay in flight)
        asm volatile("s_waitcnt lgkmcnt(0)" ::: "memory");
        __builtin_amdgcn_s_barrier();
        __builtin_amdgcn_sched_barrier(0);

        // ---- softmax: row = tid>>3, 8 cols/thread over 64 kv cols ----
        // exp2 domain (log2e folded into q); DPP reduces; m/l in registers.
        {
            const int row = tid >> 3;
            const int cp  = tid & 7;
            if (row >= 32 || j <= jL){
                const float4 x0 = *reinterpret_cast<const float4*>(&s_lds[row][8 * cp]);
                const float4 x1 = *reinterpret_cast<const float4*>(&s_lds[row][8 * cp + 4]);
                float av[8] = {x0.x, x0.y, x0.z, x0.w, x1.x, x1.y, x1.z, x1.w};
                const int qrow = (row < 32) ? (q0a + row) : (q0b + row - 32);
                const int kc = k0 + 8 * cp;
                #pragma unroll
                for (int jj = 0; jj < 8; ++jj)
                    if (kc + jj > qrow) av[jj] = -1e30f;
                float pm = fmaxf(fmaxf(fmaxf(av[0], av[1]), fmaxf(av[2], av[3])),
                                 fmaxf(fmaxf(av[4], av[5]), fmaxf(av[6], av[7])));
                pm = dppmax<0xB1>(pm); pm = dppmax<0x4E>(pm); pm = dppmax<0x141>(pm);
                const float mo = m_reg;
                const float mn = fmaxf(mo, pm);
                float e[8];
                #pragma unroll
                for (int jj = 0; jj < 8; ++jj) e[jj] = exp2fast(av[jj] - mn);
                float ts = ((e[0] + e[1]) + (e[2] + e[3])) + ((e[4] + e[5]) + (e[6] + e[7]));
                ts = dppadd<0xB1>(ts); ts = dppadd<0x4E>(ts); ts = dppadd<0x141>(ts);
                const float fc = exp2fast(mo - mn);
                m_reg = mn;
                l_reg = l_reg * fc + ts;
                if (cp == 0) fac_lds[row] = fc;
                uint4 pk;
                pk.x = (unsigned int)f2bf(e[0]) | ((unsigned int)f2bf(e[1]) << 16);
                pk.y = (unsigned int)f2bf(e[2]) | ((unsigned int)f2bf(e[3]) << 16);
                pk.z = (unsigned int)f2bf(e[4]) | ((unsigned int)f2bf(e[5]) << 16);
                pk.w = (unsigned int)f2bf(e[6]) | ((unsigned int)f2bf(e[7]) << 16);
                *reinterpret_cast<uint4*>(reinterpret_cast<char*>(p_lds) +
                    row * 128 + ((cp * 16) ^ ((row & 7) << 4))) = pk;
            }
        }
        // b2: P/fac visible AND prefetched K landed (8 glds drained; 8 V loads in flight)
        asm volatile("s_waitcnt vmcnt(8)" ::: "memory");
        asm volatile("s_waitcnt lgkmcnt(0)" ::: "memory");
        __builtin_amdgcn_s_barrier();
        __builtin_amdgcn_sched_barrier(0);
    }

    // publish register l to LDS for the epilogue's (different) thread mapping
    if ((tid & 7) == 0) l_lds[tid >> 3] = l_reg;

    // final PV (softmax/V of pair n2-1)
    asm volatile("s_waitcnt vmcnt(0)" ::: "memory");
    do_pv(n2 - 1);
    __syncthreads();   // l_lds visible to all

    // ---- finalize: /l, +residual, LN, store (64 rows) ----
    float li[4][4];
    #pragma unroll
    for (int rt = 0; rt < 4; ++rt)
        #pragma unroll
        for (int r = 0; r < 4; ++r)
            li[rt][r] = 1.0f / l_lds[16 * rt + 4 * g + r];
    #pragma unroll
    for (int rt = 0; rt < 4; ++rt){
        #pragma unroll
        for (int cv = 0; cv < 4; ++cv){
            #pragma unroll
            for (int r = 0; r < 4; ++r){
                const int row = 16 * rt + 4 * g + r;
                const int qglob = (row < 32) ? (q0a + row) : (q0b + row - 32);
                const int d = 64 * wv + 16 * cv + lr;
                acc[rt][cv][r] = acc[rt][cv][r] * li[rt][r]
                               + qin[(size_t)(b * SEQ + qglob) * DIM + d];
            }
        }
    }
    __syncthreads();   // s_lds reads fully done (aliased by red1/red2 below)
    #pragma unroll
    for (int rt = 0; rt < 4; ++rt){
        #pragma unroll
        for (int r = 0; r < 4; ++r){
            float s1 = 0.f, s2 = 0.f;
            #pragma unroll
            for (int cv = 0; cv < 4; ++cv){ const float v = acc[rt][cv][r]; s1 += v; s2 += v * v; }
            s1 = dppadd<0xB1>(s1); s1 = dppadd<0x4E>(s1); s1 = dppadd<0x141>(s1); s1 = dppadd<0x140>(s1);
            s2 = dppadd<0xB1>(s2); s2 = dppadd<0x4E>(s2); s2 = dppadd<0x141>(s2); s2 = dppadd<0x140>(s2);
            if (lr == 0){
                const int row = 16 * rt + 4 * g + r;
                red1[row * 8 + wv] = s1;
                red2[row * 8 + wv] = s2;
            }
        }
    }
    __syncthreads();
    if (tid < 64){
        float S1 = 0.f, S2 = 0.f;
        #pragma unroll
        for (int w = 0; w < 8; ++w){ S1 += red1[tid * 8 + w]; S2 += red2[tid * 8 + w]; }
        const float mu = S1 * (1.0f / 512.0f);
        const float var = S2 * (1.0f / 512.0f) - mu * mu;
        stat_mu[tid] = mu;
        stat_rs[tid] = rsqrtf(var + 1e-5f);
    }
    __syncthreads();
    #pragma unroll
    for (int rt = 0; rt < 4; ++rt){
        #pragma unroll
        for (int r = 0; r < 4; ++r){
            const int row = 16 * rt + 4 * g + r;
            const int qglob = (row < 32) ? (q0a + row) : (q0b + row - 32);
            const float mu = stat_mu[row];
            const float rs = stat_rs[row];
            #pragma unroll
            for (int cv = 0; cv < 4; ++cv){
                const int d = 64 * wv + 16 * cv + lr;
                outp[(size_t)(b * SEQ + qglob) * DIM + d] =
                    (acc[rt][cv][r] - mu) * rs * g_o[d] + b_o[d];
            }
        }
    }
}

extern "C" void kernel_launch(void* const* d_in, const int* in_sizes, int n_in,
                              void* d_out, int out_size, void* d_ws, size_t ws_size,
                              hipStream_t stream)
{
    (void)in_sizes; (void)n_in; (void)out_size; (void)ws_size;
    const float* vals = (const float*)d_in[0];
    const float* keys = (const float*)d_in[1];
    const float* ques = (const float*)d_in[2];
    const float* Wv   = (const float*)d_in[5];
    const float* Wk   = (const float*)d_in[6];
    const float* Wq   = (const float*)d_in[7];
    const float* ln_k_g = (const float*)d_in[8];
    const float* ln_k_b = (const float*)d_in[9];
    const float* ln_q_g = (const float*)d_in[10];
    const float* ln_q_b = (const float*)d_in[11];
    const float* ln_o_g = (const float*)d_in[12];
    const float* ln_o_b = (const float*)d_in[13];
    float* outp = (float*)d_out;

    char* ws = (char*)d_ws;
    unsigned short* qbuf = (unsigned short*)(ws);
    unsigned short* kbuf = (unsigned short*)(ws + (size_t)16 * 1024 * 1024);
    unsigned short* vt   = (unsigned short*)(ws + (size_t)32 * 1024 * 1024);
    unsigned short* Wt   = (unsigned short*)(ws + (size_t)48 * 1024 * 1024);

    prep_w<<<dim3(64, 3), 256, 0, stream>>>(Wv, Wk, Wq, Wt);

    gemm3<<<768, 512, 0, stream>>>(vals, keys, ques, Wt,
                                   ln_k_g, ln_k_b, ln_q_g, ln_q_b,
                                   vt, kbuf, qbuf);

    attn<<<256, 512, 0, stream>>>(qbuf, kbuf, vt, ques, ln_o_g, ln_o_b, outp);
}